// Round 4
// baseline (1970.889 us; speedup 1.0000x reference)
//
#include <hip/hip_runtime.h>

typedef unsigned short u16;
typedef unsigned int   u32;

#define DI static __device__ __forceinline__

// ---- problem constants ----
// B=16, C=32, DW=64, H=256, W=256, HW=65536. ALL inputs fp32, output fp32.
// x3 intermediate (gated tensor, 16*32*65536 fp32 = 128 MiB) lives in d_out:
// k_front writes it, k_back consumes and overwrites with the final output
// (identical per-thread index mapping; reads precede writes per thread).

// ---- workspace layout (float offsets); total ~445 KiB ----
static constexpr int OFF_SSUM = 0;        // 16*32 = 512
static constexpr int OFF_SCALE = 512;     // 512
static constexpr int OFF_W1 = 1024;       // 16*64*32 = 32768
static constexpr int OFF_B1 = 33792;      // 1024
static constexpr int OFF_W2 = 34816;      // 16*64*9 = 9216
static constexpr int OFF_B2 = 44032;      // 1024
static constexpr int OFF_W3 = 45056;      // 16*32*32 = 16384
static constexpr int OFF_B3 = 61440;      // 512
static constexpr int OFF_W4 = 61952;      // 32768
static constexpr int OFF_B4 = 94720;      // 1024
static constexpr int OFF_W5 = 95744;      // 16384
static constexpr int OFF_B5 = 112128;     // 512
static constexpr int OFF_N1W = 112640;    // 32
static constexpr int OFF_N1B = 112672;    // 32
static constexpr int OFF_N2W = 112704;    // 32
static constexpr int OFF_N2B = 112736;    // 32
static constexpr int OFF_SCAW = 112768;   // 1024
static constexpr int OFF_SCAB = 113792;   // 32
static constexpr int OFF_BETA = 113824;   // 32
static constexpr int OFF_GAMMA = 113856;  // 32  (end = 113888 floats)

DI u16 f2bf(float f) {
  u32 x = __float_as_uint(f);
  u32 r = (x + 0x7fffu + ((x >> 16) & 1u)) >> 16;  // RNE
  return (u16)r;
}

struct WPtrs {
  const float *w1, *b1, *w2, *b2, *w3, *b3, *w4, *b4, *w5, *b5;
  const float *n1w, *n1b, *n2w, *n2b, *scaw, *scab, *beta, *gamma;
};

DI void cpy_seg(float* dst, const float* src, int n, int tid, int stride) {
  for (int i = tid; i < n; i += stride) dst[i] = src[i];
}

// ---- K0: gather all weights into contiguous fp32 ws; zero SE accumulators ----
__global__ __launch_bounds__(256) void k_pack(WPtrs p, float* __restrict__ wf) {
  const int tid = blockIdx.x * 256 + threadIdx.x;
  const int stride = gridDim.x * 256;
  for (int i = tid; i < 512; i += stride) wf[OFF_SSUM + i] = 0.0f;
  cpy_seg(wf + OFF_W1, p.w1, 32768, tid, stride);
  cpy_seg(wf + OFF_B1, p.b1, 1024, tid, stride);
  cpy_seg(wf + OFF_W2, p.w2, 9216, tid, stride);
  cpy_seg(wf + OFF_B2, p.b2, 1024, tid, stride);
  cpy_seg(wf + OFF_W3, p.w3, 16384, tid, stride);
  cpy_seg(wf + OFF_B3, p.b3, 512, tid, stride);
  cpy_seg(wf + OFF_W4, p.w4, 32768, tid, stride);
  cpy_seg(wf + OFF_B4, p.b4, 1024, tid, stride);
  cpy_seg(wf + OFF_W5, p.w5, 16384, tid, stride);
  cpy_seg(wf + OFF_B5, p.b5, 512, tid, stride);
  cpy_seg(wf + OFF_N1W, p.n1w, 32, tid, stride);
  cpy_seg(wf + OFF_N1B, p.n1b, 32, tid, stride);
  cpy_seg(wf + OFF_N2W, p.n2w, 32, tid, stride);
  cpy_seg(wf + OFF_N2B, p.n2b, 32, tid, stride);
  cpy_seg(wf + OFF_SCAW, p.scaw, 1024, tid, stride);
  cpy_seg(wf + OFF_SCAB, p.scab, 32, tid, stride);
  cpy_seg(wf + OFF_BETA, p.beta, 32, tid, stride);
  cpy_seg(wf + OFF_GAMMA, p.gamma, 32, tid, stride);
}

// ---- K1: LN1 + conv1x1(32->64) + dwconv3x3 + SimpleGate -> x3 (fp32, in d_out);
// per-(b,c) channel sums for SE. Tile 32x8 interior, 34x10 with halo. Conv1 output
// kept in LDS as packed bf16 pairs (ch c lo16, ch c+32 hi16): one ds_read_b32
// yields both gate halves per tap.
__global__ __launch_bounds__(256) void k_front(const float* __restrict__ inp,
                                               const float* __restrict__ wf,
                                               float* __restrict__ x3,
                                               float* ssum) {
  const int tid = threadIdx.x;
  const int b = blockIdx.y;
  const int tile = blockIdx.x;        // 8 tiles in x, 32 in y
  const int tx = tile & 7, ty = tile >> 3;
  const int gx0 = tx * 32 - 1, gy0 = ty * 8 - 1;

  __shared__ u32 x1p[32][340];  // [pair][py*34+px]

  const float* w1 = wf + OFF_W1 + b * 2048;
  const float* b1 = wf + OFF_B1 + b * 64;
  const float* n1w = wf + OFF_N1W;
  const float* n1b = wf + OFF_N1B;

#pragma unroll 1
  for (int idx = tid; idx < 340; idx += 256) {
    const int py = idx / 34;
    const int px = idx - py * 34;
    const int gy = gy0 + py, gx = gx0 + px;
    if ((u32)gy >= 256u || (u32)gx >= 256u) {
#pragma unroll
      for (int c = 0; c < 32; c++) x1p[c][idx] = 0u;
    } else {
      const float* src = inp + (((size_t)(b * 32)) << 16) + (gy << 8) + gx;
      float x[32];
      float s = 0.f, s2 = 0.f;
#pragma unroll
      for (int c = 0; c < 32; c++) {
        float v = src[(size_t)c << 16];
        x[c] = v; s += v; s2 += v * v;
      }
      const float mu = s * (1.f / 32.f);
      const float var = fmaxf(s2 * (1.f / 32.f) - mu * mu, 0.f);
      const float rstd = rsqrtf(var + 1e-6f);
#pragma unroll
      for (int c = 0; c < 32; c++) x[c] = (x[c] - mu) * rstd * n1w[c] + n1b[c];
#pragma unroll
      for (int o = 0; o < 32; o++) {
        float a0 = b1[o], a1 = b1[o + 32];
#pragma unroll
        for (int c = 0; c < 32; c++) {
          a0 += x[c] * w1[o * 32 + c];
          a1 += x[c] * w1[(o + 32) * 32 + c];
        }
        x1p[o][idx] = (u32)f2bf(a0) | ((u32)f2bf(a1) << 16);
      }
    }
  }
  __syncthreads();

  const int px = tid & 31, py = tid >> 5;  // 32x8 interior
  const int p = (py + 1) * 34 + (px + 1);
  const int gpix = ((ty * 8 + py) << 8) + (tx * 32 + px);
  const float* w2 = wf + OFF_W2 + b * 576;
  const float* b2 = wf + OFF_B2 + b * 64;
  float* ob = x3 + (((size_t)(b * 32)) << 16) + gpix;
  float* sb = ssum + b * 32;

#pragma unroll 2
  for (int c = 0; c < 32; c++) {
    float a1 = b2[c], a2 = b2[c + 32];
    const int offs[9] = {-35, -34, -33, -1, 0, 1, 33, 34, 35};
#pragma unroll
    for (int k = 0; k < 9; k++) {
      const u32 u = x1p[c][p + offs[k]];
      const float lo = __uint_as_float(u << 16);
      const float hi = __uint_as_float(u & 0xffff0000u);
      a1 += lo * w2[c * 9 + k];
      a2 += hi * w2[(c + 32) * 9 + k];
    }
    const float v = a1 * a2;  // SimpleGate
    ob[(size_t)c << 16] = v;
    float r = v;
#pragma unroll
    for (int off = 32; off > 0; off >>= 1) r += __shfl_xor(r, off, 64);
    if ((tid & 63) == 0) atomicAdd(&sb[c], r);
  }
}

// ---- K2: SE head: mean -> 32x32 matmul -> per-(b,c) scale ----
__global__ __launch_bounds__(512) void k_sca(float* __restrict__ wf) {
  const int t = threadIdx.x;  // 512 = 16*32
  const int b = t >> 5, o = t & 31;
  const float* sw = wf + OFF_SCAW;
  float acc = wf[OFF_SCAB + o];
#pragma unroll
  for (int c = 0; c < 32; c++)
    acc += (wf[OFF_SSUM + b * 32 + c] * (1.f / 65536.f)) * sw[o * 32 + c];
  wf[OFF_SCALE + b * 32 + o] = acc;
}

// ---- K3: scale*x3 -> conv3 -> beta-res -> LN2 -> conv4 -> SG -> conv5 -> gamma-res ----
// x3 and out are the SAME buffer (d_out). No __restrict__ on them: per-thread
// program order (all x3 reads precede all out writes) must be preserved, and
// different threads touch disjoint (b,pix) element sets.
__global__ __launch_bounds__(256) void k_back(const float* __restrict__ inp,
                                              const float* x3,
                                              const float* __restrict__ wf,
                                              float* out) {
  const int tid = threadIdx.x;
  const int b = blockIdx.y;
  const int pix = blockIdx.x * 256 + tid;
  const size_t base = (((size_t)(b * 32)) << 16) + pix;

  const float* sc = wf + OFF_SCALE + b * 32;
  const float* w3 = wf + OFF_W3 + b * 1024;
  const float* b3 = wf + OFF_B3 + b * 32;
  const float* w4 = wf + OFF_W4 + b * 2048;
  const float* b4 = wf + OFF_B4 + b * 64;
  const float* w5 = wf + OFF_W5 + b * 1024;
  const float* b5 = wf + OFF_B5 + b * 32;
  const float* n2w = wf + OFF_N2W;
  const float* n2b = wf + OFF_N2B;
  const float* be = wf + OFF_BETA;
  const float* ga = wf + OFF_GAMMA;

  float xa[32];
#pragma unroll
  for (int c = 0; c < 32; c++) xa[c] = x3[base + ((size_t)c << 16)] * sc[c];

  float y[32];
  float s = 0.f, s2 = 0.f;
#pragma unroll
  for (int o = 0; o < 32; o++) {
    float a = b3[o];
#pragma unroll
    for (int c = 0; c < 32; c++) a += xa[c] * w3[o * 32 + c];
    const float yo = inp[base + ((size_t)o << 16)] + a * be[o];
    y[o] = yo; s += yo; s2 += yo * yo;
  }
  const float mu = s * (1.f / 32.f);
  const float var = fmaxf(s2 * (1.f / 32.f) - mu * mu, 0.f);
  const float rstd = rsqrtf(var + 1e-6f);

  float z[32];
#pragma unroll
  for (int c = 0; c < 32; c++) z[c] = (y[c] - mu) * rstd * n2w[c] + n2b[c];

  float g[32];
#pragma unroll
  for (int o = 0; o < 32; o++) {
    float a0 = b4[o], a1 = b4[o + 32];
#pragma unroll
    for (int c = 0; c < 32; c++) {
      a0 += z[c] * w4[o * 32 + c];
      a1 += z[c] * w4[(o + 32) * 32 + c];
    }
    g[o] = a0 * a1;  // SimpleGate
  }

#pragma unroll
  for (int o = 0; o < 32; o++) {
    float a = b5[o];
#pragma unroll
    for (int j = 0; j < 32; j++) a += g[j] * w5[o * 32 + j];
    out[base + ((size_t)o << 16)] = y[o] + a * ga[o];
  }
}

extern "C" void kernel_launch(void* const* d_in, const int* in_sizes, int n_in,
                              void* d_out, int out_size, void* d_ws, size_t ws_size,
                              hipStream_t stream) {
  (void)in_sizes; (void)n_in; (void)out_size; (void)ws_size;
  const float* inp = (const float*)d_in[0];
  WPtrs p;
  p.w1 = (const float*)d_in[1];  p.b1 = (const float*)d_in[2];
  p.w2 = (const float*)d_in[3];  p.b2 = (const float*)d_in[4];
  p.w3 = (const float*)d_in[5];  p.b3 = (const float*)d_in[6];
  p.w4 = (const float*)d_in[7];  p.b4 = (const float*)d_in[8];
  p.w5 = (const float*)d_in[9];  p.b5 = (const float*)d_in[10];
  p.n1w = (const float*)d_in[11]; p.n1b = (const float*)d_in[12];
  p.n2w = (const float*)d_in[13]; p.n2b = (const float*)d_in[14];
  p.scaw = (const float*)d_in[15]; p.scab = (const float*)d_in[16];
  p.beta = (const float*)d_in[17]; p.gamma = (const float*)d_in[18];

  float* wf = (float*)d_ws;
  float* x3 = (float*)d_out;   // fp32 x3 lives in d_out (exact 128 MiB fit)
  float* out = (float*)d_out;

  k_pack<<<dim3(128), dim3(256), 0, stream>>>(p, wf);
  k_front<<<dim3(256, 16), dim3(256), 0, stream>>>(inp, wf, x3, wf + OFF_SSUM);
  k_sca<<<dim3(1), dim3(512), 0, stream>>>(wf);
  k_back<<<dim3(256, 16), dim3(256), 0, stream>>>(inp, x3, wf, out);
}